// Round 1
// baseline (481.259 us; speedup 1.0000x reference)
//
#include <hip/hip_runtime.h>
#include <hip/hip_bf16.h>

#define N_NODES 6144
#define IN_F 256
#define N_HEADS 4
#define N_HID 64

typedef __attribute__((ext_vector_type(8))) short short8;
typedef __attribute__((ext_vector_type(4))) float floatx4;

__device__ __forceinline__ short f2bf_bits(float f) {
    union { float f; unsigned u; } v; v.f = f;
    unsigned r = v.u + 0x7fffu + ((v.u >> 16) & 1u);
    return (short)(r >> 16);
}

// ---------------- Kernel 1: ht = h @ W (fp32), epilogue -> htT bf16 (transposed), src, tgt
__global__ __launch_bounds__(256) void ht_gemm_kernel(
    const float* __restrict__ h, const float* __restrict__ W,
    const float* __restrict__ a, __hip_bfloat16* __restrict__ htT,
    float* __restrict__ srcv, float* __restrict__ tgtv)
{
    __shared__ float As[32][68];   // [k][m]
    __shared__ float Bs[32][68];   // [k][n]
    __shared__ float redS[64][16];
    __shared__ float redT[64][16];

    const int head = blockIdx.y;
    const int i0 = blockIdx.x * 64;
    const int tid = threadIdx.x;
    const int tx = tid & 15, ty = tid >> 4;

    float acc[4][4] = {};

    for (int k0 = 0; k0 < IN_F; k0 += 32) {
        __syncthreads();
        // As[k][m] = h[(i0+m)*256 + k0+k]
        #pragma unroll
        for (int it = 0; it < 2; ++it) {
            int l = it * 256 + tid;
            int m = l >> 3;       // 0..63
            int kq = l & 7;       // 0..7
            const float4 v = *(const float4*)(h + (i0 + m) * IN_F + k0 + kq * 4);
            As[kq*4+0][m] = v.x; As[kq*4+1][m] = v.y;
            As[kq*4+2][m] = v.z; As[kq*4+3][m] = v.w;
        }
        // Bs[k][n] = W[(k0+k)*256 + head*64 + n]
        #pragma unroll
        for (int it = 0; it < 2; ++it) {
            int l = it * 256 + tid;
            int k = l >> 4;       // 0..31
            int nq = l & 15;      // 0..15
            *(float4*)&Bs[k][nq*4] = *(const float4*)(W + (k0 + k) * 256 + head * 64 + nq * 4);
        }
        __syncthreads();
        #pragma unroll
        for (int kk = 0; kk < 32; ++kk) {
            const float4 av = *(const float4*)&As[kk][ty*4];
            const float4 bv = *(const float4*)&Bs[kk][tx*4];
            const float aa[4] = {av.x, av.y, av.z, av.w};
            const float bb[4] = {bv.x, bv.y, bv.z, bv.w};
            #pragma unroll
            for (int r = 0; r < 4; ++r)
                #pragma unroll
                for (int c = 0; c < 4; ++c)
                    acc[r][c] = fmaf(aa[r], bb[c], acc[r][c]);
        }
    }

    // epilogue: htT[(head*64+d)*6144 + i] bf16
    #pragma unroll
    for (int r = 0; r < 4; ++r)
        #pragma unroll
        for (int c = 0; c < 4; ++c) {
            const int d = tx * 4 + c;
            const int i = i0 + ty * 4 + r;
            htT[(head * N_HID + d) * N_NODES + i] = __float2bfloat16(acc[r][c]);
        }

    // src/tgt: dot over d with a_src/a_tgt
    float as_[4], at_[4];
    #pragma unroll
    for (int c = 0; c < 4; ++c) {
        as_[c] = a[head * 128 + tx * 4 + c];
        at_[c] = a[head * 128 + 64 + tx * 4 + c];
    }
    #pragma unroll
    for (int r = 0; r < 4; ++r) {
        float ps = 0.f, pt = 0.f;
        #pragma unroll
        for (int c = 0; c < 4; ++c) {
            ps = fmaf(acc[r][c], as_[c], ps);
            pt = fmaf(acc[r][c], at_[c], pt);
        }
        redS[ty*4+r][tx] = ps;
        redT[ty*4+r][tx] = pt;
    }
    __syncthreads();
    if (tid < 128) {
        const int row = tid & 63;
        const float* src = (tid < 64) ? &redS[row][0] : &redT[row][0];
        float s = 0.f;
        #pragma unroll
        for (int x = 0; x < 16; ++x) s += src[x];
        if (tid < 64) srcv[head * N_NODES + i0 + row] = s;
        else          tgtv[head * N_NODES + i0 + row] = s;
    }
}

// ---------------- Kernel 2: masked rank-1 softmax + PV via MFMA
// grid.x = 384 i-tiles of 16 rows; block = (64,4): wave y handles head y.
__global__ __launch_bounds__(256) void gat_main_kernel(
    const int* __restrict__ adj, const __hip_bfloat16* __restrict__ htT,
    const float* __restrict__ srcv, const float* __restrict__ tgtv,
    float* __restrict__ num, float* __restrict__ den)
{
    const int lane = threadIdx.x;   // 0..63
    const int head = threadIdx.y;   // 0..3
    const int i0 = blockIdx.x * 16;
    const int m = lane & 15, quad = lane >> 4;
    const int row = i0 + m;

    const float src_val = srcv[head * N_NODES + row];
    const int* adj_row = adj + (size_t)row * N_NODES;
    const float* tgt_row = tgtv + head * N_NODES;
    // B fragment: B[k][n], n = lane&15, k = quad*8+idx  (htT[h][d][j], d = c*16+n)
    const short* hbs = (const short*)htT + (size_t)(head * N_HID + m) * N_NODES;

    floatx4 acc0 = {0,0,0,0}, acc1 = {0,0,0,0}, acc2 = {0,0,0,0}, acc3 = {0,0,0,0};
    float denp = 0.f;

    for (int j0 = 0; j0 < N_NODES; j0 += 32) {
        const int jb = j0 + quad * 8;
        const int4 a0 = *(const int4*)(adj_row + jb);
        const int4 a1 = *(const int4*)(adj_row + jb + 4);
        const float4 t0 = *(const float4*)(tgt_row + jb);
        const float4 t1 = *(const float4*)(tgt_row + jb + 4);
        const int   av[8] = {a0.x, a0.y, a0.z, a0.w, a1.x, a1.y, a1.z, a1.w};
        const float tv[8] = {t0.x, t0.y, t0.z, t0.w, t1.x, t1.y, t1.z, t1.w};

        short8 af;
        #pragma unroll
        for (int u = 0; u < 8; ++u) {
            float e = src_val + tv[u];
            e = fmaxf(e, 0.2f * e);          // leakyrelu
            float ww = __expf(e);
            ww = (av[u] > 0) ? ww : 0.f;     // mask: exp(-inf) = 0
            denp += ww;
            af[u] = f2bf_bits(ww);
        }

        const short8 b0 = *(const short8*)(hbs + (size_t)0 * 16 * N_NODES + jb);
        const short8 b1 = *(const short8*)(hbs + (size_t)1 * 16 * N_NODES + jb);
        const short8 b2 = *(const short8*)(hbs + (size_t)2 * 16 * N_NODES + jb);
        const short8 b3 = *(const short8*)(hbs + (size_t)3 * 16 * N_NODES + jb);

        acc0 = __builtin_amdgcn_mfma_f32_16x16x32_bf16(af, b0, acc0, 0, 0, 0);
        acc1 = __builtin_amdgcn_mfma_f32_16x16x32_bf16(af, b1, acc1, 0, 0, 0);
        acc2 = __builtin_amdgcn_mfma_f32_16x16x32_bf16(af, b2, acc2, 0, 0, 0);
        acc3 = __builtin_amdgcn_mfma_f32_16x16x32_bf16(af, b3, acc3, 0, 0, 0);
    }

    // denominator: reduce the 4 quad-partials per row
    denp += __shfl_xor(denp, 16, 64);
    denp += __shfl_xor(denp, 32, 64);
    if (quad == 0) den[head * N_NODES + row] = denp;

    // numerator: C/D layout col=lane&15, row=quad*4+r
    #pragma unroll
    for (int r = 0; r < 4; ++r) {
        const int gi = i0 + quad * 4 + r;
        float* np_ = num + (size_t)(head * N_NODES + gi) * N_HID + (lane & 15);
        np_[0]  = acc0[r];
        np_[16] = acc1[r];
        np_[32] = acc2[r];
        np_[48] = acc3[r];
    }
}

// ---------------- Kernel 3: out[i][d] = mean_h num[h][i][d]/den[h][i]
__global__ __launch_bounds__(256) void finalize_kernel(
    const float* __restrict__ num, const float* __restrict__ den,
    float* __restrict__ out)
{
    const int idx = blockIdx.x * 256 + threadIdx.x;
    if (idx >= N_NODES * N_HID) return;
    const int i = idx >> 6;
    const int d = idx & 63;
    float s = 0.f;
    #pragma unroll
    for (int hh = 0; hh < N_HEADS; ++hh)
        s += num[(size_t)(hh * N_NODES + i) * N_HID + d] / den[hh * N_NODES + i];
    out[idx] = 0.25f * s;
}

extern "C" void kernel_launch(void* const* d_in, const int* in_sizes, int n_in,
                              void* d_out, int out_size, void* d_ws, size_t ws_size,
                              hipStream_t stream)
{
    const float* h   = (const float*)d_in[0];
    const int*   adj = (const int*)d_in[1];
    const float* W   = (const float*)d_in[2];
    const float* a   = (const float*)d_in[3];
    float* out = (float*)d_out;

    char* ws = (char*)d_ws;
    // layout: htT bf16 [4][64][6144] | src f32 [4][6144] | tgt f32 [4][6144]
    //         | num f32 [4][6144][64] | den f32 [4][6144]   (total ~9.3 MB)
    __hip_bfloat16* htT = (__hip_bfloat16*)ws;
    size_t off = (size_t)N_HEADS * N_HID * N_NODES * 2;             // 3,145,728
    float* srcv = (float*)(ws + off);  off += (size_t)N_HEADS * N_NODES * 4;
    float* tgtv = (float*)(ws + off);  off += (size_t)N_HEADS * N_NODES * 4;
    float* num  = (float*)(ws + off);  off += (size_t)N_HEADS * N_NODES * N_HID * 4;
    float* den  = (float*)(ws + off);

    ht_gemm_kernel<<<dim3(N_NODES / 64, N_HEADS), 256, 0, stream>>>(h, W, a, htT, srcv, tgtv);
    gat_main_kernel<<<dim3(N_NODES / 16), dim3(64, 4), 0, stream>>>(adj, htT, srcv, tgtv, num, den);
    finalize_kernel<<<dim3((N_NODES * N_HID) / 256), 256, 0, stream>>>(num, den, out);
}

// Round 2
// 428.250 us; speedup vs baseline: 1.1238x; 1.1238x over previous
//
#include <hip/hip_runtime.h>
#include <hip/hip_bf16.h>

#define N_NODES 6144
#define IN_F 256
#define N_HEADS 4
#define N_HID 64

typedef __attribute__((ext_vector_type(8))) short short8;
typedef __attribute__((ext_vector_type(4))) float floatx4;

__device__ __forceinline__ short f2bf_bits(float f) {
    union { float f; unsigned u; } v; v.f = f;
    unsigned r = v.u + 0x7fffu + ((v.u >> 16) & 1u);
    return (short)(r >> 16);
}

// ---------------- Kernel 1: ht = h @ W (fp32), epilogue -> htT bf16 (transposed), src, tgt
__global__ __launch_bounds__(256) void ht_gemm_kernel(
    const float* __restrict__ h, const float* __restrict__ W,
    const float* __restrict__ a, __hip_bfloat16* __restrict__ htT,
    float* __restrict__ srcv, float* __restrict__ tgtv)
{
    __shared__ float As[32][68];   // [k][m]
    __shared__ float Bs[32][68];   // [k][n]
    __shared__ float redS[64][16];
    __shared__ float redT[64][16];

    const int head = blockIdx.y;
    const int i0 = blockIdx.x * 64;
    const int tid = threadIdx.x;
    const int tx = tid & 15, ty = tid >> 4;

    float acc[4][4] = {};

    for (int k0 = 0; k0 < IN_F; k0 += 32) {
        __syncthreads();
        #pragma unroll
        for (int it = 0; it < 2; ++it) {
            int l = it * 256 + tid;
            int m = l >> 3;       // 0..63
            int kq = l & 7;       // 0..7
            const float4 v = *(const float4*)(h + (i0 + m) * IN_F + k0 + kq * 4);
            As[kq*4+0][m] = v.x; As[kq*4+1][m] = v.y;
            As[kq*4+2][m] = v.z; As[kq*4+3][m] = v.w;
        }
        #pragma unroll
        for (int it = 0; it < 2; ++it) {
            int l = it * 256 + tid;
            int k = l >> 4;       // 0..31
            int nq = l & 15;      // 0..15
            *(float4*)&Bs[k][nq*4] = *(const float4*)(W + (k0 + k) * 256 + head * 64 + nq * 4);
        }
        __syncthreads();
        #pragma unroll
        for (int kk = 0; kk < 32; ++kk) {
            const float4 av = *(const float4*)&As[kk][ty*4];
            const float4 bv = *(const float4*)&Bs[kk][tx*4];
            const float aa[4] = {av.x, av.y, av.z, av.w};
            const float bb[4] = {bv.x, bv.y, bv.z, bv.w};
            #pragma unroll
            for (int r = 0; r < 4; ++r)
                #pragma unroll
                for (int c = 0; c < 4; ++c)
                    acc[r][c] = fmaf(aa[r], bb[c], acc[r][c]);
        }
    }

    #pragma unroll
    for (int r = 0; r < 4; ++r)
        #pragma unroll
        for (int c = 0; c < 4; ++c) {
            const int d = tx * 4 + c;
            const int i = i0 + ty * 4 + r;
            htT[(head * N_HID + d) * N_NODES + i] = __float2bfloat16(acc[r][c]);
        }

    float as_[4], at_[4];
    #pragma unroll
    for (int c = 0; c < 4; ++c) {
        as_[c] = a[head * 128 + tx * 4 + c];
        at_[c] = a[head * 128 + 64 + tx * 4 + c];
    }
    #pragma unroll
    for (int r = 0; r < 4; ++r) {
        float ps = 0.f, pt = 0.f;
        #pragma unroll
        for (int c = 0; c < 4; ++c) {
            ps = fmaf(acc[r][c], as_[c], ps);
            pt = fmaf(acc[r][c], at_[c], pt);
        }
        redS[ty*4+r][tx] = ps;
        redT[ty*4+r][tx] = pt;
    }
    __syncthreads();
    if (tid < 128) {
        const int row = tid & 63;
        const float* src = (tid < 64) ? &redS[row][0] : &redT[row][0];
        float s = 0.f;
        #pragma unroll
        for (int x = 0; x < 16; ++x) s += src[x];
        if (tid < 64) srcv[head * N_NODES + i0 + row] = s;
        else          tgtv[head * N_NODES + i0 + row] = s;
    }
}

// ---------------- Kernel 2: masked rank-1 softmax + PV via MFMA, j-split for occupancy
// grid = (384 i-tiles, JS j-chunks); block = (64,4): wave y = head y.
// Writes partial num/den per (j-chunk, head).
__global__ __launch_bounds__(256) void gat_main_kernel(
    const int* __restrict__ adj, const __hip_bfloat16* __restrict__ htT,
    const float* __restrict__ srcv, const float* __restrict__ tgtv,
    float* __restrict__ pnum, float* __restrict__ pden, int jlen)
{
    const int lane = threadIdx.x;   // 0..63
    const int head = threadIdx.y;   // 0..3
    const int jc = blockIdx.y;
    const int i0 = blockIdx.x * 16;
    const int m = lane & 15, quad = lane >> 4;
    const int row = i0 + m;
    const int jbase = jc * jlen;

    const float src_val = srcv[head * N_NODES + row];
    const int* adj_row = adj + (size_t)row * N_NODES;
    const float* tgt_row = tgtv + head * N_NODES;
    // B fragment: B[k][n], n = lane&15, k = quad*8+idx  (htT[h][d][j], d = c*16+n)
    const short* hbs = (const short*)htT + (size_t)(head * N_HID + m) * N_NODES;

    floatx4 acc0 = {0,0,0,0}, acc1 = {0,0,0,0}, acc2 = {0,0,0,0}, acc3 = {0,0,0,0};
    float denp = 0.f;

    for (int j0 = 0; j0 < jlen; j0 += 32) {
        const int jb = jbase + j0 + quad * 8;
        const int4 a0 = *(const int4*)(adj_row + jb);
        const int4 a1 = *(const int4*)(adj_row + jb + 4);
        const float4 t0 = *(const float4*)(tgt_row + jb);
        const float4 t1 = *(const float4*)(tgt_row + jb + 4);
        const int   av[8] = {a0.x, a0.y, a0.z, a0.w, a1.x, a1.y, a1.z, a1.w};
        const float tv[8] = {t0.x, t0.y, t0.z, t0.w, t1.x, t1.y, t1.z, t1.w};

        short8 af;
        #pragma unroll
        for (int u = 0; u < 8; ++u) {
            float e = src_val + tv[u];
            e = fmaxf(e, 0.2f * e);          // leakyrelu
            float ww = __expf(e);
            ww = (av[u] > 0) ? ww : 0.f;     // mask: exp(-inf) = 0
            denp += ww;
            af[u] = f2bf_bits(ww);
        }

        const short8 b0 = *(const short8*)(hbs + (size_t)0 * 16 * N_NODES + jb);
        const short8 b1 = *(const short8*)(hbs + (size_t)1 * 16 * N_NODES + jb);
        const short8 b2 = *(const short8*)(hbs + (size_t)2 * 16 * N_NODES + jb);
        const short8 b3 = *(const short8*)(hbs + (size_t)3 * 16 * N_NODES + jb);

        acc0 = __builtin_amdgcn_mfma_f32_16x16x32_bf16(af, b0, acc0, 0, 0, 0);
        acc1 = __builtin_amdgcn_mfma_f32_16x16x32_bf16(af, b1, acc1, 0, 0, 0);
        acc2 = __builtin_amdgcn_mfma_f32_16x16x32_bf16(af, b2, acc2, 0, 0, 0);
        acc3 = __builtin_amdgcn_mfma_f32_16x16x32_bf16(af, b3, acc3, 0, 0, 0);
    }

    const int slot = jc * N_HEADS + head;

    // denominator: reduce the 4 quad-partials per row
    denp += __shfl_xor(denp, 16, 64);
    denp += __shfl_xor(denp, 32, 64);
    if (quad == 0) pden[slot * N_NODES + row] = denp;

    // numerator partial: C/D layout col=lane&15, row=quad*4+r
    #pragma unroll
    for (int r = 0; r < 4; ++r) {
        const int gi = i0 + quad * 4 + r;
        float* np_ = pnum + ((size_t)slot * N_NODES + gi) * N_HID + (lane & 15);
        np_[0]  = acc0[r];
        np_[16] = acc1[r];
        np_[32] = acc2[r];
        np_[48] = acc3[r];
    }
}

// ---------------- Kernel 3: reduce j-chunks, divide, mean over heads
__global__ __launch_bounds__(256) void finalize_kernel(
    const float* __restrict__ pnum, const float* __restrict__ pden,
    float* __restrict__ out, int js)
{
    const int idx = blockIdx.x * 256 + threadIdx.x;
    if (idx >= N_NODES * N_HID) return;
    const int i = idx >> 6;
    const int d = idx & 63;
    float s = 0.f;
    for (int hh = 0; hh < N_HEADS; ++hh) {
        float ns = 0.f, ds = 0.f;
        for (int jc = 0; jc < js; ++jc) {
            const int slot = jc * N_HEADS + hh;
            ns += pnum[((size_t)slot * N_NODES + i) * N_HID + d];
            ds += pden[slot * N_NODES + i];
        }
        s += ns / ds;
    }
    out[idx] = 0.25f * s;
}

extern "C" void kernel_launch(void* const* d_in, const int* in_sizes, int n_in,
                              void* d_out, int out_size, void* d_ws, size_t ws_size,
                              hipStream_t stream)
{
    const float* h   = (const float*)d_in[0];
    const int*   adj = (const int*)d_in[1];
    const float* W   = (const float*)d_in[2];
    const float* a   = (const float*)d_in[3];
    float* out = (float*)d_out;

    char* ws = (char*)d_ws;
    // layout: htT bf16 [4][64][6144] | src f32 [4][6144] | tgt f32 [4][6144]
    //         | pnum f32 [JS][4][6144][64] | pden f32 [JS][4][6144]
    __hip_bfloat16* htT = (__hip_bfloat16*)ws;
    size_t off = (size_t)N_HEADS * N_HID * N_NODES * 2;             // 3,145,728
    float* srcv = (float*)(ws + off);  off += (size_t)N_HEADS * N_NODES * 4;
    float* tgtv = (float*)(ws + off);  off += (size_t)N_HEADS * N_NODES * 4;

    const size_t per_js = (size_t)N_HEADS * N_NODES * N_HID * 4 + (size_t)N_HEADS * N_NODES * 4;
    int js = 4;                       // j-split factor; degrade if ws too small
    while (js > 1 && off + (size_t)js * per_js > ws_size) js >>= 1;
    const int jlen = N_NODES / js;

    float* pnum = (float*)(ws + off);  off += (size_t)js * N_HEADS * N_NODES * N_HID * 4;
    float* pden = (float*)(ws + off);

    ht_gemm_kernel<<<dim3(N_NODES / 64, N_HEADS), 256, 0, stream>>>(h, W, a, htT, srcv, tgtv);
    gat_main_kernel<<<dim3(N_NODES / 16, js), dim3(64, 4), 0, stream>>>(adj, htT, srcv, tgtv, pnum, pden, jlen);
    finalize_kernel<<<dim3((N_NODES * N_HID) / 256), 256, 0, stream>>>(pnum, pden, out, js);
}

// Round 3
// 334.992 us; speedup vs baseline: 1.4366x; 1.2784x over previous
//
#include <hip/hip_runtime.h>
#include <hip/hip_bf16.h>

#define N_NODES 6144
#define IN_F 256
#define N_HEADS 4
#define N_HID 64
#define NWORDS32 (N_NODES / 32)   // 192 u32 mask words per row

typedef __attribute__((ext_vector_type(8))) short short8;
typedef __attribute__((ext_vector_type(4))) float floatx4;

__device__ __forceinline__ short f2bf_bits(float f) {
    union { float f; unsigned u; } v; v.f = f;
    unsigned r = v.u + 0x7fffu + ((v.u >> 16) & 1u);
    return (short)(r >> 16);
}

// ---------------- Kernel 0: pack adj int32 -> bitmask (151MB -> 4.7MB)
__global__ __launch_bounds__(256) void pack_adj_kernel(
    const int* __restrict__ adj, unsigned long long* __restrict__ mask64, int nwords)
{
    const int gtid = blockIdx.x * 256 + threadIdx.x;
    const int wave = gtid >> 6;
    const int lane = threadIdx.x & 63;
    const int nwaves = (gridDim.x * 256) >> 6;
    for (int w = wave; w < nwords; w += nwaves) {
        const int v = adj[(size_t)w * 64 + lane];
        const unsigned long long b = __ballot(v > 0);
        if (lane == 0) mask64[w] = b;
    }
}

// ---------------- Kernel 1: ht = h @ W (fp32); epilogue -> htF (MFMA B-fragment layout), src, tgt
// htF flat index F(head, jt, c, n, q, u) = ((((head*192 + jt)*4 + c)*16 + n)*4 + q)*8 + u
//   where node j = jt*32 + q*8 + u, feature d = c*16 + n.
// In kernel 2, lane (m + 16*quad) reads 16B at base(head,jt,c) + (m*4+quad)*16B -> fully coalesced 1KB.
__global__ __launch_bounds__(256) void ht_gemm_kernel(
    const float* __restrict__ h, const float* __restrict__ W,
    const float* __restrict__ a, short* __restrict__ htF,
    float* __restrict__ srcv, float* __restrict__ tgtv)
{
    __shared__ float As[32][68];   // [k][m]
    __shared__ float Bs[32][68];   // [k][n]
    __shared__ float redS[64][16];
    __shared__ float redT[64][16];

    const int head = blockIdx.y;
    const int i0 = blockIdx.x * 64;
    const int tid = threadIdx.x;
    const int tx = tid & 15, ty = tid >> 4;

    float acc[4][4] = {};

    for (int k0 = 0; k0 < IN_F; k0 += 32) {
        __syncthreads();
        #pragma unroll
        for (int it = 0; it < 2; ++it) {
            int l = it * 256 + tid;
            int m = l >> 3;       // 0..63
            int kq = l & 7;       // 0..7
            const float4 v = *(const float4*)(h + (i0 + m) * IN_F + k0 + kq * 4);
            As[kq*4+0][m] = v.x; As[kq*4+1][m] = v.y;
            As[kq*4+2][m] = v.z; As[kq*4+3][m] = v.w;
        }
        #pragma unroll
        for (int it = 0; it < 2; ++it) {
            int l = it * 256 + tid;
            int k = l >> 4;       // 0..31
            int nq = l & 15;      // 0..15
            *(float4*)&Bs[k][nq*4] = *(const float4*)(W + (k0 + k) * 256 + head * 64 + nq * 4);
        }
        __syncthreads();
        #pragma unroll
        for (int kk = 0; kk < 32; ++kk) {
            const float4 av = *(const float4*)&As[kk][ty*4];
            const float4 bv = *(const float4*)&Bs[kk][tx*4];
            const float aa[4] = {av.x, av.y, av.z, av.w};
            const float bb[4] = {bv.x, bv.y, bv.z, bv.w};
            #pragma unroll
            for (int r = 0; r < 4; ++r)
                #pragma unroll
                for (int c = 0; c < 4; ++c)
                    acc[r][c] = fmaf(aa[r], bb[c], acc[r][c]);
        }
    }

    // epilogue: scatter into fragment-major layout (bf16)
    #pragma unroll
    for (int r = 0; r < 4; ++r)
        #pragma unroll
        for (int c2 = 0; c2 < 4; ++c2) {
            const int d = tx * 4 + c2;
            const int j = i0 + ty * 4 + r;
            const int jt = j >> 5, q = (j >> 3) & 3, u = j & 7;
            const int c = d >> 4, n = d & 15;
            const size_t F = (((((size_t)head * 192 + jt) * 4 + c) * 16 + n) * 4 + q) * 8 + u;
            htF[F] = f2bf_bits(acc[r][c2]);
        }

    float as_[4], at_[4];
    #pragma unroll
    for (int c = 0; c < 4; ++c) {
        as_[c] = a[head * 128 + tx * 4 + c];
        at_[c] = a[head * 128 + 64 + tx * 4 + c];
    }
    #pragma unroll
    for (int r = 0; r < 4; ++r) {
        float ps = 0.f, pt = 0.f;
        #pragma unroll
        for (int c = 0; c < 4; ++c) {
            ps = fmaf(acc[r][c], as_[c], ps);
            pt = fmaf(acc[r][c], at_[c], pt);
        }
        redS[ty*4+r][tx] = ps;
        redT[ty*4+r][tx] = pt;
    }
    __syncthreads();
    if (tid < 128) {
        const int row = tid & 63;
        const float* src = (tid < 64) ? &redS[row][0] : &redT[row][0];
        float s = 0.f;
        #pragma unroll
        for (int x = 0; x < 16; ++x) s += src[x];
        if (tid < 64) srcv[head * N_NODES + i0 + row] = s;
        else          tgtv[head * N_NODES + i0 + row] = s;
    }
}

// ---------------- Kernel 2: masked rank-1 softmax + PV via MFMA
// grid = (384 i-tiles, JS j-chunks); block = (64,4): wave y = head y.
__global__ __launch_bounds__(256) void gat_main_kernel(
    const unsigned* __restrict__ mask32, const short* __restrict__ htF,
    const float* __restrict__ srcv, const float* __restrict__ tgtv,
    float* __restrict__ pnum, float* __restrict__ pden, int jlen)
{
    __shared__ unsigned smask[16][197];   // worst case js=1: 192 words/row; 197 odd stride

    const int lane = threadIdx.x;   // 0..63
    const int head = threadIdx.y;   // 0..3
    const int jc = blockIdx.y;
    const int i0 = blockIdx.x * 16;
    const int m = lane & 15, quad = lane >> 4;
    const int row = i0 + m;
    const int jbase = jc * jlen;
    const int nw = jlen >> 5;       // 32-col words in this chunk

    // stage this block's bitmask slice (16 rows x nw words)
    const int tid = head * 64 + lane;
    for (int t = tid; t < 16 * nw; t += 256) {
        const int r = t / nw, w = t - r * nw;
        smask[r][w] = mask32[(size_t)(i0 + r) * NWORDS32 + (jbase >> 5) + w];
    }
    __syncthreads();

    const float src_val = srcv[head * N_NODES + row];
    const float* tgt_row = tgtv + head * N_NODES;
    // coalesced fragment base: 1KB per (head, jt, c); this lane's 16B chunk
    const short* fb = htF + ((size_t)(head * 192 + (jbase >> 5)) * 4) * 512 + (m * 4 + quad) * 8;

    floatx4 acc0 = {0,0,0,0}, acc1 = {0,0,0,0}, acc2 = {0,0,0,0}, acc3 = {0,0,0,0};
    float denp = 0.f;

    for (int w = 0; w < nw; ++w) {
        const int jb = jbase + w * 32 + quad * 8;
        const unsigned bits = (smask[m][w] >> (quad * 8)) & 0xffu;
        const float4 t0 = *(const float4*)(tgt_row + jb);
        const float4 t1 = *(const float4*)(tgt_row + jb + 4);
        const short8 b0 = *(const short8*)(fb + (size_t)w * 2048);
        const short8 b1 = *(const short8*)(fb + (size_t)w * 2048 + 512);
        const short8 b2 = *(const short8*)(fb + (size_t)w * 2048 + 1024);
        const short8 b3 = *(const short8*)(fb + (size_t)w * 2048 + 1536);
        const float tv[8] = {t0.x, t0.y, t0.z, t0.w, t1.x, t1.y, t1.z, t1.w};

        short8 af;
        #pragma unroll
        for (int u = 0; u < 8; ++u) {
            float e = src_val + tv[u];
            e = fmaxf(e, 0.2f * e);            // leakyrelu
            float ww = __expf(e);
            ww = (bits & (1u << u)) ? ww : 0.f; // mask: exp(-inf) = 0
            denp += ww;
            af[u] = f2bf_bits(ww);
        }

        acc0 = __builtin_amdgcn_mfma_f32_16x16x32_bf16(af, b0, acc0, 0, 0, 0);
        acc1 = __builtin_amdgcn_mfma_f32_16x16x32_bf16(af, b1, acc1, 0, 0, 0);
        acc2 = __builtin_amdgcn_mfma_f32_16x16x32_bf16(af, b2, acc2, 0, 0, 0);
        acc3 = __builtin_amdgcn_mfma_f32_16x16x32_bf16(af, b3, acc3, 0, 0, 0);
    }

    const int slot = jc * N_HEADS + head;

    denp += __shfl_xor(denp, 16, 64);
    denp += __shfl_xor(denp, 32, 64);
    if (quad == 0) pden[slot * N_NODES + row] = denp;

    // numerator partial: C/D layout col=lane&15, row=quad*4+r
    #pragma unroll
    for (int r = 0; r < 4; ++r) {
        const int gi = i0 + quad * 4 + r;
        float* np_ = pnum + ((size_t)slot * N_NODES + gi) * N_HID + (lane & 15);
        np_[0]  = acc0[r];
        np_[16] = acc1[r];
        np_[32] = acc2[r];
        np_[48] = acc3[r];
    }
}

// ---------------- Kernel 3: reduce j-chunks, divide, mean over heads
__global__ __launch_bounds__(256) void finalize_kernel(
    const float* __restrict__ pnum, const float* __restrict__ pden,
    float* __restrict__ out, int js)
{
    const int idx = blockIdx.x * 256 + threadIdx.x;
    if (idx >= N_NODES * N_HID) return;
    const int i = idx >> 6;
    const int d = idx & 63;
    float s = 0.f;
    for (int hh = 0; hh < N_HEADS; ++hh) {
        float ns = 0.f, ds = 0.f;
        for (int jc = 0; jc < js; ++jc) {
            const int slot = jc * N_HEADS + hh;
            ns += pnum[((size_t)slot * N_NODES + i) * N_HID + d];
            ds += pden[slot * N_NODES + i];
        }
        s += ns / ds;
    }
    out[idx] = 0.25f * s;
}

extern "C" void kernel_launch(void* const* d_in, const int* in_sizes, int n_in,
                              void* d_out, int out_size, void* d_ws, size_t ws_size,
                              hipStream_t stream)
{
    const float* h   = (const float*)d_in[0];
    const int*   adj = (const int*)d_in[1];
    const float* W   = (const float*)d_in[2];
    const float* a   = (const float*)d_in[3];
    float* out = (float*)d_out;

    char* ws = (char*)d_ws;
    // layout: htF bf16 [4][192][4][16][4][8] (3.1MB) | src f32 [4][6144] | tgt f32 [4][6144]
    //         | mask64 u64 [589824] (4.7MB) | pnum f32 [JS][4][6144][64] | pden f32 [JS][4][6144]
    short* htF = (short*)ws;
    size_t off = (size_t)N_HEADS * N_HID * N_NODES * 2;             // 3,145,728
    float* srcv = (float*)(ws + off);  off += (size_t)N_HEADS * N_NODES * 4;
    float* tgtv = (float*)(ws + off);  off += (size_t)N_HEADS * N_NODES * 4;
    const int nwords64 = N_NODES * N_NODES / 64;                    // 589,824
    unsigned long long* mask64 = (unsigned long long*)(ws + off);
    off += (size_t)nwords64 * 8;

    const size_t per_js = (size_t)N_HEADS * N_NODES * N_HID * 4 + (size_t)N_HEADS * N_NODES * 4;
    int js = 4;
    while (js > 1 && off + (size_t)js * per_js > ws_size) js >>= 1;
    const int jlen = N_NODES / js;

    float* pnum = (float*)(ws + off);  off += (size_t)js * N_HEADS * N_NODES * N_HID * 4;
    float* pden = (float*)(ws + off);

    pack_adj_kernel<<<2048, 256, 0, stream>>>(adj, mask64, nwords64);
    ht_gemm_kernel<<<dim3(N_NODES / 64, N_HEADS), 256, 0, stream>>>(h, W, a, htF, srcv, tgtv);
    gat_main_kernel<<<dim3(N_NODES / 16, js), dim3(64, 4), 0, stream>>>(
        (const unsigned*)mask64, htF, srcv, tgtv, pnum, pden, jlen);
    finalize_kernel<<<dim3((N_NODES * N_HID) / 256), 256, 0, stream>>>(pnum, pden, out, js);
}